// Round 1
// baseline (9668.653 us; speedup 1.0000x reference)
//
#include <hip/hip_runtime.h>
#include <cstdint>
#include <cstddef>

#define D_ 768
#define NH_ 12
#define HD_ 64
#define S_ 197
#define LTOK_ 196
#define FF_ 3072
#define NIMG_ 16
#define OUT_ 512
#define LAYERS_ 12

typedef unsigned short u16;
typedef __bf16 bf16x8 __attribute__((ext_vector_type(8)));
typedef float f32x4 __attribute__((ext_vector_type(4)));

__device__ __forceinline__ u16 f2bf(float f) {
  uint32_t u = __builtin_bit_cast(uint32_t, f);
  u = (u + 0x7FFFu + ((u >> 16) & 1u)) >> 16;
  return (u16)u;
}
__device__ __forceinline__ void unp2(uint32_t u, float& a, float& b) {
  a = __builtin_bit_cast(float, u << 16);
  b = __builtin_bit_cast(float, u & 0xFFFF0000u);
}

typedef __attribute__((address_space(3))) void lvoid;
typedef __attribute__((address_space(1))) void gvoid;
// global -> LDS direct copy, 16B per lane. LDS dest must be wave-uniform base + lane*16,
// which our t*16 layout satisfies. Casts go through integers (inttoptr is always legal);
// flat LDS address low 32 bits == LDS offset on gfx9+.
__device__ __forceinline__ void async16(const u16* g, u16* l) {
  __builtin_amdgcn_global_load_lds((gvoid*)(uintptr_t)g,
                                   (lvoid*)(uint32_t)(uintptr_t)l, 16, 0, 0);
}

// ---------------- fp32 -> bf16 convert ----------------
__global__ __launch_bounds__(256) void cvt_kernel(const float* __restrict__ src,
                                                  u16* __restrict__ dst, int n4) {
  int i = blockIdx.x * 256 + threadIdx.x;
  if (i >= n4) return;
  const float4 v = ((const float4*)src)[i];
  ushort4 o;
  o.x = f2bf(v.x); o.y = f2bf(v.y); o.z = f2bf(v.z); o.w = f2bf(v.w);
  ((ushort4*)dst)[i] = o;
}

// ---------------- im2col for patch conv ----------------
__global__ __launch_bounds__(256) void im2col_kernel(const float* __restrict__ mimg,
                                                     const float* __restrict__ pimg,
                                                     u16* __restrict__ Xp) {
  const int row = blockIdx.x;                 // 0..6271  (n*196 + l)
  const int n = row / LTOK_, l = row % LTOK_;
  const float* img = (n < NIMG_) ? (mimg + (size_t)n * 3 * 224 * 224)
                                 : (pimg + (size_t)(n - NIMG_) * 3 * 224 * 224);
  const int gy = l / 14, gx = l % 14;
  for (int col = threadIdx.x; col < D_; col += 256) {
    const int c = col >> 8, py = (col >> 4) & 15, px = col & 15;
    Xp[(size_t)row * D_ + col] = f2bf(img[c * 50176 + (gy * 16 + py) * 224 + gx * 16 + px]);
  }
}

// ---------------- GEMM: C = A(M,K) @ Bw(N,K)^T (+epilogue) ----------------
// EPI: 0 = raw fp32 store; 1 = +bias -> bf16; 2 = +bias, gelu(sigmoid) -> bf16;
//      3 = +bias + residual (fp32 in-place)
template <int EPI>
__global__ __launch_bounds__(256, 2) void gemm_bt(const u16* __restrict__ A,
                                                  const u16* __restrict__ Bw,
                                                  const float* __restrict__ bias,
                                                  float* __restrict__ Cf,
                                                  u16* __restrict__ Cb,
                                                  int M, int N, int K) {
  __shared__ __align__(16) u16 As[128 * 32];
  __shared__ __align__(16) u16 Bs[128 * 32];
  const int t = threadIdx.x, lane = t & 63, w = t >> 6;
  const int wm = (w >> 1) << 6, wn = (w & 1) << 6;
  const int mBase = blockIdx.y << 7, nBase = blockIdx.x << 7;
  f32x4 acc[4][4];
  const f32x4 z = {0.f, 0.f, 0.f, 0.f};
#pragma unroll
  for (int i = 0; i < 4; i++)
#pragma unroll
    for (int j = 0; j < 4; j++) acc[i][j] = z;

  const int lr = t >> 2, lc = (t & 3) << 3;
  const u16* Ag = A + (size_t)(mBase + lr) * K + lc;
  const u16* Bg = Bw + (size_t)(nBase + lr) * K + lc;
  const size_t halfs = (size_t)64 * K;
  u16* Al = As + t * 8;
  u16* Bl = Bs + t * 8;
  const int q8 = (lane >> 4) << 3, r16 = lane & 15;

  for (int k0 = 0; k0 < K; k0 += 32) {
    async16(Ag, Al);  async16(Ag + halfs, Al + 2048);
    async16(Bg, Bl);  async16(Bg + halfs, Bl + 2048);
    Ag += 32; Bg += 32;
    __syncthreads();
    bf16x8 af[4], bfr[4];
#pragma unroll
    for (int mt = 0; mt < 4; mt++)
      af[mt] = *(const bf16x8*)(As + (wm + mt * 16 + r16) * 32 + q8);
#pragma unroll
    for (int nt = 0; nt < 4; nt++)
      bfr[nt] = *(const bf16x8*)(Bs + (wn + nt * 16 + r16) * 32 + q8);
#pragma unroll
    for (int mt = 0; mt < 4; mt++)
#pragma unroll
      for (int nt = 0; nt < 4; nt++)
        acc[mt][nt] = __builtin_amdgcn_mfma_f32_16x16x32_bf16(af[mt], bfr[nt], acc[mt][nt], 0, 0, 0);
    __syncthreads();
  }

  const int colB = nBase + wn + r16;
  const int rowB = mBase + wm + ((lane >> 4) << 2);
#pragma unroll
  for (int nt = 0; nt < 4; nt++) {
    const int col = colB + nt * 16;
    const float bv = (EPI == 0) ? 0.f : bias[col];
#pragma unroll
    for (int mt = 0; mt < 4; mt++) {
#pragma unroll
      for (int r = 0; r < 4; r++) {
        const int row = rowB + mt * 16 + r;
        const size_t o = (size_t)row * N + col;
        const float v = acc[mt][nt][r];
        if (EPI == 0) {
          Cf[o] = v;
        } else if (EPI == 1) {
          Cb[o] = f2bf(v + bv);
        } else if (EPI == 2) {
          const float hh = v + bv;
          Cb[o] = f2bf(hh / (1.f + __expf(-1.702f * hh)));
        } else {
          Cf[o] += v + bv;
        }
      }
    }
  }
}

// ---------------- LayerNorm over rows of 768 ----------------
__device__ __forceinline__ void st_ln(float* p, float v) { *p = v; }
__device__ __forceinline__ void st_ln(u16* p, float v) { *p = f2bf(v); }

template <typename OT>
__global__ __launch_bounds__(256) void ln_rows(const float* __restrict__ x, size_t strideIn,
                                               OT* __restrict__ y, size_t strideOut,
                                               const float* __restrict__ gw,
                                               const float* __restrict__ bw) {
  const int row = blockIdx.x, t = threadIdx.x;
  const float* xr = x + (size_t)row * strideIn;
  float v0 = xr[t], v1 = xr[t + 256], v2 = xr[t + 512];
  float s1 = v0 + v1 + v2;
  float s2 = v0 * v0 + v1 * v1 + v2 * v2;
#pragma unroll
  for (int off = 1; off < 64; off <<= 1) {
    s1 += __shfl_xor(s1, off);
    s2 += __shfl_xor(s2, off);
  }
  __shared__ float as1[4], as2[4];
  const int lane = t & 63, w = t >> 6;
  if (lane == 0) { as1[w] = s1; as2[w] = s2; }
  __syncthreads();
  s1 = as1[0] + as1[1] + as1[2] + as1[3];
  s2 = as2[0] + as2[1] + as2[2] + as2[3];
  const float mu = s1 * (1.f / 768.f);
  const float rs = rsqrtf(fmaxf(s2 * (1.f / 768.f) - mu * mu, 0.f) + 1e-5f);
  OT* yr = y + (size_t)row * strideOut;
  st_ln(yr + t, (v0 - mu) * rs * gw[t] + bw[t]);
  st_ln(yr + t + 256, (v1 - mu) * rs * gw[t + 256] + bw[t + 256]);
  st_ln(yr + t + 512, (v2 - mu) * rs * gw[t + 512] + bw[t + 512]);
}

// ---------------- assemble x = [cls; tok] + pos ----------------
__global__ __launch_bounds__(256) void assemble_x(const float* __restrict__ tokf,
                                                  const float* __restrict__ cls,
                                                  const float* __restrict__ pos,
                                                  float* __restrict__ x12) {
  const int row = blockIdx.x;  // n*197 + s
  const int n = row / S_, s = row % S_;
  for (int d = threadIdx.x; d < D_; d += 256) {
    float v = (s == 0) ? cls[d] : tokf[(size_t)(n * LTOK_ + s - 1) * D_ + d];
    x12[(size_t)row * D_ + d] = v + pos[s * D_ + d];
  }
}

// ---------------- xa = xa + 2 * (s==0 ? xb : xb*pm) ----------------
__global__ __launch_bounds__(256) void combine_kernel(float* __restrict__ xa,
                                                      const float* __restrict__ xb,
                                                      const float* __restrict__ pm) {
  const int row = blockIdx.x;  // b*197 + s, b<16
  const int b = row / S_, s = row % S_;
  const float m2 = (s == 0) ? 2.f : 2.f * pm[b * LTOK_ + s - 1];
  for (int d = threadIdx.x; d < D_; d += 256) {
    const size_t o = (size_t)row * D_ + d;
    xa[o] += m2 * xb[o];
  }
}

// ---------------- attention: one block per (b,h) ----------------
__global__ __launch_bounds__(256, 2) void attn_kernel(const u16* __restrict__ qkv,
                                                      u16* __restrict__ out,
                                                      const float* __restrict__ pm,
                                                      int useBias) {
  __shared__ __align__(16) u16 Ks[S_ * 72];
  __shared__ __align__(16) u16 Vs[S_ * 72];
  __shared__ float Ps[4][200];
  const int bh = blockIdx.x, b = bh / NH_, h = bh % NH_;
  const int t = threadIdx.x, lane = t & 63, w = t >> 6;
  const u16* base = qkv + (size_t)b * S_ * 2304 + h * HD_;
  for (int i = t; i < S_ * 8; i += 256) {
    const int j = i >> 3, seg = (i & 7) << 3;
    const u16* rp = base + (size_t)j * 2304 + seg;
    *(uint4*)&Ks[j * 72 + seg] = *(const uint4*)(rp + D_);
    *(uint4*)&Vs[j * 72 + seg] = *(const uint4*)(rp + 2 * D_);
  }
  __syncthreads();
  const int half = lane >> 5, d2 = (lane & 31) << 1;
  const int j0 = half ? 99 : 0, j1 = half ? S_ : 99;
  for (int q = w; q < S_; q += 4) {
    const u16* qp = base + (size_t)q * 2304;
    float qf[64];
#pragma unroll
    for (int i = 0; i < 8; i++) {
      uint4 u = *(const uint4*)(qp + i * 8);
      unp2(u.x, qf[i * 8 + 0], qf[i * 8 + 1]);
      unp2(u.y, qf[i * 8 + 2], qf[i * 8 + 3]);
      unp2(u.z, qf[i * 8 + 4], qf[i * 8 + 5]);
      unp2(u.w, qf[i * 8 + 6], qf[i * 8 + 7]);
    }
    float sc[4];
#pragma unroll
    for (int jj = 0; jj < 4; jj++) {
      const int j = lane + (jj << 6);
      float acc = -3.0e38f;
      if (j < S_) {
        const u16* kr = &Ks[j * 72];
        acc = 0.f;
#pragma unroll
        for (int i = 0; i < 8; i++) {
          uint4 u = *(const uint4*)(kr + i * 8);
          float a0, a1;
          unp2(u.x, a0, a1); acc += qf[i * 8 + 0] * a0 + qf[i * 8 + 1] * a1;
          unp2(u.y, a0, a1); acc += qf[i * 8 + 2] * a0 + qf[i * 8 + 3] * a1;
          unp2(u.z, a0, a1); acc += qf[i * 8 + 4] * a0 + qf[i * 8 + 5] * a1;
          unp2(u.w, a0, a1); acc += qf[i * 8 + 6] * a0 + qf[i * 8 + 7] * a1;
        }
        acc *= 0.125f;
        if (useBias && q == 0 && j >= 1)
          acc += (pm[b * LTOK_ + j - 1] != 0.f) ? 0.f : -1e30f;
      }
      sc[jj] = acc;
    }
    float mx = fmaxf(fmaxf(sc[0], sc[1]), fmaxf(sc[2], sc[3]));
#pragma unroll
    for (int off = 1; off < 64; off <<= 1) mx = fmaxf(mx, __shfl_xor(mx, off));
    float e[4], sum = 0.f;
#pragma unroll
    for (int jj = 0; jj < 4; jj++) { e[jj] = __expf(sc[jj] - mx); sum += e[jj]; }
#pragma unroll
    for (int off = 1; off < 64; off <<= 1) sum += __shfl_xor(sum, off);
    const float inv = 1.f / sum;
#pragma unroll
    for (int jj = 0; jj < 4; jj++) {
      const int j = lane + (jj << 6);
      if (j < S_) Ps[w][j] = e[jj] * inv;
    }
    float o0 = 0.f, o1 = 0.f;
    for (int j = j0; j < j1; j++) {
      const float p = Ps[w][j];
      const uint32_t vv = *(const uint32_t*)&Vs[j * 72 + d2];
      float a0, a1; unp2(vv, a0, a1);
      o0 += p * a0; o1 += p * a1;
    }
    o0 += __shfl_xor(o0, 32);
    o1 += __shfl_xor(o1, 32);
    if (lane < 32) {
      const uint32_t pk = (uint32_t)f2bf(o0) | ((uint32_t)f2bf(o1) << 16);
      *(uint32_t*)(out + (size_t)(b * S_ + q) * D_ + h * HD_ + d2) = pk;
    }
  }
}

// ---------------- final: out = cls_ln @ proj (768x512), fp32 ----------------
__global__ __launch_bounds__(256) void final_proj_kernel(const float* __restrict__ clsn,
                                                         const float* __restrict__ proj,
                                                         float* __restrict__ outp) {
  __shared__ float cs[D_];
  const int b = blockIdx.x;
  for (int d = threadIdx.x; d < D_; d += 256) cs[d] = clsn[b * D_ + d];
  __syncthreads();
  for (int o = threadIdx.x; o < OUT_; o += 256) {
    float acc = 0.f;
    for (int d = 0; d < D_; d++) acc += cs[d] * proj[d * OUT_ + o];
    outp[b * OUT_ + o] = acc;
  }
}

extern "C" void kernel_launch(void* const* d_in, const int* in_sizes, int n_in,
                              void* d_out, int out_size, void* d_ws, size_t ws_size,
                              hipStream_t stream) {
  (void)in_sizes; (void)n_in; (void)out_size; (void)ws_size;
  const float* masked   = (const float*)d_in[0];
  const float* prompted = (const float*)d_in[1];
  const float* pmasks   = (const float*)d_in[2];
  const float* conv_w   = (const float*)d_in[3];
  const float* class_emb= (const float*)d_in[4];
  const float* pos_emb  = (const float*)d_in[5];
  const float* ln_pre_g = (const float*)d_in[6];
  const float* ln_pre_b = (const float*)d_in[7];
  const float* Wqkv     = (const float*)d_in[8];
  const float* bqkv     = (const float*)d_in[9];
  const float* Wo       = (const float*)d_in[10];
  const float* bo       = (const float*)d_in[11];
  const float* ln1_g    = (const float*)d_in[12];
  const float* ln1_b    = (const float*)d_in[13];
  const float* ln2_g    = (const float*)d_in[14];
  const float* ln2_b    = (const float*)d_in[15];
  const float* Wfc      = (const float*)d_in[16];
  const float* bfc      = (const float*)d_in[17];
  const float* Wp       = (const float*)d_in[18];
  const float* bp       = (const float*)d_in[19];
  const float* ln_post_g= (const float*)d_in[20];
  const float* ln_post_b= (const float*)d_in[21];
  const float* projw    = (const float*)d_in[22];

  char* pws = (char*)d_ws;
  auto take = [&](size_t bytes) { char* r = pws; pws += (bytes + 255) & ~(size_t)255; return r; };
  u16*   wqkv_all = (u16*)take((size_t)LAYERS_ * 2304 * D_ * 2);
  u16*   wo_all   = (u16*)take((size_t)LAYERS_ * D_ * D_ * 2);
  u16*   wfc_all  = (u16*)take((size_t)LAYERS_ * FF_ * D_ * 2);
  u16*   wp_all   = (u16*)take((size_t)LAYERS_ * D_ * FF_ * 2);
  u16*   wc       = (u16*)take((size_t)D_ * D_ * 2);
  u16*   Xp       = (u16*)take((size_t)6272 * D_ * 2);
  float* tokf     = (float*)take((size_t)6272 * D_ * 4);
  float* x12      = (float*)take((size_t)6400 * D_ * 4);
  u16*   xn       = (u16*)take((size_t)6400 * D_ * 2);
  u16*   qkvb     = (u16*)take((size_t)6400 * 2304 * 2);
  u16*   ao       = (u16*)take((size_t)6400 * D_ * 2);
  u16*   hb       = (u16*)take((size_t)6400 * FF_ * 2);
  float* xa       = (float*)take((size_t)3200 * D_ * 4);
  float* xb       = (float*)take((size_t)3200 * D_ * 4);
  float* clsn     = (float*)take((size_t)16 * D_ * 4);

  auto cvt = [&](const float* s, u16* d, size_t n) {
    int n4 = (int)(n >> 2);
    cvt_kernel<<<dim3((n4 + 255) / 256), dim3(256), 0, stream>>>(s, d, n4);
  };
  cvt(Wqkv,   wqkv_all, (size_t)LAYERS_ * 2304 * D_);
  cvt(Wo,     wo_all,   (size_t)LAYERS_ * D_ * D_);
  cvt(Wfc,    wfc_all,  (size_t)LAYERS_ * FF_ * D_);
  cvt(Wp,     wp_all,   (size_t)LAYERS_ * D_ * FF_);
  cvt(conv_w, wc,       (size_t)D_ * D_);

  // patch embed for both image sets (32 images)
  im2col_kernel<<<dim3(6272), dim3(256), 0, stream>>>(masked, prompted, Xp);
  gemm_bt<0><<<dim3(6, 49), dim3(256), 0, stream>>>(Xp, wc, nullptr, tokf, nullptr, 6272, D_, D_);
  assemble_x<<<dim3(32 * S_), dim3(256), 0, stream>>>(tokf, class_emb, pos_emb, x12);
  ln_rows<float><<<dim3(32 * S_), dim3(256), 0, stream>>>(x12, D_, x12, D_, ln_pre_g, ln_pre_b);

  auto run_block = [&](float* x, int Mp, int Mv, int Batt, int li, int useBias) {
    const int gy = Mp / 128;
    ln_rows<u16><<<dim3(Mv), dim3(256), 0, stream>>>(x, D_, xn, D_, ln1_g + li * D_, ln1_b + li * D_);
    gemm_bt<1><<<dim3(18, gy), dim3(256), 0, stream>>>(
        xn, wqkv_all + (size_t)li * 2304 * D_, bqkv + li * 2304, nullptr, qkvb, Mp, 2304, D_);
    attn_kernel<<<dim3(Batt * NH_), dim3(256), 0, stream>>>(qkvb, ao, pmasks, useBias);
    gemm_bt<3><<<dim3(6, gy), dim3(256), 0, stream>>>(
        ao, wo_all + (size_t)li * D_ * D_, bo + li * D_, x, nullptr, Mp, D_, D_);
    ln_rows<u16><<<dim3(Mv), dim3(256), 0, stream>>>(x, D_, xn, D_, ln2_g + li * D_, ln2_b + li * D_);
    gemm_bt<2><<<dim3(24, gy), dim3(256), 0, stream>>>(
        xn, wfc_all + (size_t)li * FF_ * D_, bfc + li * FF_, nullptr, hb, Mp, FF_, D_);
    gemm_bt<3><<<dim3(6, gy), dim3(256), 0, stream>>>(
        hb, wp_all + (size_t)li * D_ * FF_, bp + li * D_, x, nullptr, Mp, D_, FF_);
  };

  for (int li = 0; li < 10; li++) run_block(x12, 6400, 32 * S_, 32, li, 0);

  // split into x (masked path) and x2 (prompted path)
  hipMemcpyAsync(xa, x12, (size_t)NIMG_ * S_ * D_ * 4, hipMemcpyDeviceToDevice, stream);
  hipMemcpyAsync(xb, x12 + (size_t)NIMG_ * S_ * D_, (size_t)NIMG_ * S_ * D_ * 4,
                 hipMemcpyDeviceToDevice, stream);

  for (int li = 10; li <= 11; li++) {
    combine_kernel<<<dim3(NIMG_ * S_), dim3(256), 0, stream>>>(xa, xb, pmasks);
    run_block(xa, 3200, NIMG_ * S_, NIMG_, li, 0);
    run_block(xb, 3200, NIMG_ * S_, NIMG_, li, 1);
  }

  ln_rows<float><<<dim3(16), dim3(256), 0, stream>>>(xa, (size_t)S_ * D_, clsn, D_,
                                                     ln_post_g, ln_post_b);
  final_proj_kernel<<<dim3(16), dim3(256), 0, stream>>>(clsn, projw, (float*)d_out);
}

// Round 2
// 3876.820 us; speedup vs baseline: 2.4940x; 2.4940x over previous
//
#include <hip/hip_runtime.h>
#include <cstdint>
#include <cstddef>

#define D_ 768
#define NH_ 12
#define HD_ 64
#define S_ 197
#define LTOK_ 196
#define FF_ 3072
#define NIMG_ 16
#define OUT_ 512
#define LAYERS_ 12

typedef unsigned short u16;
typedef __bf16 bf16x8 __attribute__((ext_vector_type(8)));
typedef float f32x4 __attribute__((ext_vector_type(4)));
typedef u16 u16x8 __attribute__((ext_vector_type(8)));

__device__ __forceinline__ u16 f2bf(float f) {
  uint32_t u = __builtin_bit_cast(uint32_t, f);
  u = (u + 0x7FFFu + ((u >> 16) & 1u)) >> 16;
  return (u16)u;
}

typedef __attribute__((address_space(3))) void lvoid;
typedef __attribute__((address_space(1))) void gvoid;
__device__ __forceinline__ void async16(const u16* g, u16* l) {
  __builtin_amdgcn_global_load_lds((gvoid*)(uintptr_t)g,
                                   (lvoid*)(uint32_t)(uintptr_t)l, 16, 0, 0);
}

// ---------------- fp32 -> bf16 convert ----------------
__global__ __launch_bounds__(256) void cvt_kernel(const float* __restrict__ src,
                                                  u16* __restrict__ dst, int n4) {
  int i = blockIdx.x * 256 + threadIdx.x;
  if (i >= n4) return;
  const float4 v = ((const float4*)src)[i];
  ushort4 o;
  o.x = f2bf(v.x); o.y = f2bf(v.y); o.z = f2bf(v.z); o.w = f2bf(v.w);
  ((ushort4*)dst)[i] = o;
}

// ---------------- im2col for patch conv ----------------
__global__ __launch_bounds__(256) void im2col_kernel(const float* __restrict__ mimg,
                                                     const float* __restrict__ pimg,
                                                     u16* __restrict__ Xp) {
  const int row = blockIdx.x;                 // 0..6271  (n*196 + l)
  const int n = row / LTOK_, l = row % LTOK_;
  const float* img = (n < NIMG_) ? (mimg + (size_t)n * 3 * 224 * 224)
                                 : (pimg + (size_t)(n - NIMG_) * 3 * 224 * 224);
  const int gy = l / 14, gx = l % 14;
  for (int col = threadIdx.x; col < D_; col += 256) {
    const int c = col >> 8, py = (col >> 4) & 15, px = col & 15;
    Xp[(size_t)row * D_ + col] = f2bf(img[c * 50176 + (gy * 16 + py) * 224 + gx * 16 + px]);
  }
}

// ---------------- GEMM: C = A(M,K) @ Bw(N,K)^T (+epilogue) ----------------
template <int EPI>
__global__ __launch_bounds__(256, 2) void gemm_bt(const u16* __restrict__ A,
                                                  const u16* __restrict__ Bw,
                                                  const float* __restrict__ bias,
                                                  float* __restrict__ Cf,
                                                  u16* __restrict__ Cb,
                                                  int M, int N, int K) {
  __shared__ __align__(16) u16 As[128 * 32];
  __shared__ __align__(16) u16 Bs[128 * 32];
  const int t = threadIdx.x, lane = t & 63, w = t >> 6;
  const int wm = (w >> 1) << 6, wn = (w & 1) << 6;
  const int mBase = blockIdx.y << 7, nBase = blockIdx.x << 7;
  f32x4 acc[4][4];
  const f32x4 z = {0.f, 0.f, 0.f, 0.f};
#pragma unroll
  for (int i = 0; i < 4; i++)
#pragma unroll
    for (int j = 0; j < 4; j++) acc[i][j] = z;

  const int lr = t >> 2, lc = (t & 3) << 3;
  const u16* Ag = A + (size_t)(mBase + lr) * K + lc;
  const u16* Bg = Bw + (size_t)(nBase + lr) * K + lc;
  const size_t halfs = (size_t)64 * K;
  u16* Al = As + t * 8;
  u16* Bl = Bs + t * 8;
  const int q8 = (lane >> 4) << 3, r16 = lane & 15;

  for (int k0 = 0; k0 < K; k0 += 32) {
    async16(Ag, Al);  async16(Ag + halfs, Al + 2048);
    async16(Bg, Bl);  async16(Bg + halfs, Bl + 2048);
    Ag += 32; Bg += 32;
    __syncthreads();
    bf16x8 af[4], bfr[4];
#pragma unroll
    for (int mt = 0; mt < 4; mt++)
      af[mt] = *(const bf16x8*)(As + (wm + mt * 16 + r16) * 32 + q8);
#pragma unroll
    for (int nt = 0; nt < 4; nt++)
      bfr[nt] = *(const bf16x8*)(Bs + (wn + nt * 16 + r16) * 32 + q8);
#pragma unroll
    for (int mt = 0; mt < 4; mt++)
#pragma unroll
      for (int nt = 0; nt < 4; nt++)
        acc[mt][nt] = __builtin_amdgcn_mfma_f32_16x16x32_bf16(af[mt], bfr[nt], acc[mt][nt], 0, 0, 0);
    __syncthreads();
  }

  const int colB = nBase + wn + r16;
  const int rowB = mBase + wm + ((lane >> 4) << 2);
#pragma unroll
  for (int nt = 0; nt < 4; nt++) {
    const int col = colB + nt * 16;
    const float bv = (EPI == 0) ? 0.f : bias[col];
#pragma unroll
    for (int mt = 0; mt < 4; mt++) {
#pragma unroll
      for (int r = 0; r < 4; r++) {
        const int row = rowB + mt * 16 + r;
        const size_t o = (size_t)row * N + col;
        const float v = acc[mt][nt][r];
        if (EPI == 0) {
          Cf[o] = v;
        } else if (EPI == 1) {
          Cb[o] = f2bf(v + bv);
        } else if (EPI == 2) {
          const float hh = v + bv;
          Cb[o] = f2bf(hh / (1.f + __expf(-1.702f * hh)));
        } else {
          Cf[o] += v + bv;
        }
      }
    }
  }
}

// ---------------- LayerNorm over rows of 768 ----------------
__device__ __forceinline__ void st_ln(float* p, float v) { *p = v; }
__device__ __forceinline__ void st_ln(u16* p, float v) { *p = f2bf(v); }

template <typename OT>
__global__ __launch_bounds__(256) void ln_rows(const float* __restrict__ x, size_t strideIn,
                                               OT* __restrict__ y, size_t strideOut,
                                               const float* __restrict__ gw,
                                               const float* __restrict__ bw) {
  const int row = blockIdx.x, t = threadIdx.x;
  const float* xr = x + (size_t)row * strideIn;
  float v0 = xr[t], v1 = xr[t + 256], v2 = xr[t + 512];
  float s1 = v0 + v1 + v2;
  float s2 = v0 * v0 + v1 * v1 + v2 * v2;
#pragma unroll
  for (int off = 1; off < 64; off <<= 1) {
    s1 += __shfl_xor(s1, off);
    s2 += __shfl_xor(s2, off);
  }
  __shared__ float as1[4], as2[4];
  const int lane = t & 63, w = t >> 6;
  if (lane == 0) { as1[w] = s1; as2[w] = s2; }
  __syncthreads();
  s1 = as1[0] + as1[1] + as1[2] + as1[3];
  s2 = as2[0] + as2[1] + as2[2] + as2[3];
  const float mu = s1 * (1.f / 768.f);
  const float rs = rsqrtf(fmaxf(s2 * (1.f / 768.f) - mu * mu, 0.f) + 1e-5f);
  OT* yr = y + (size_t)row * strideOut;
  st_ln(yr + t, (v0 - mu) * rs * gw[t] + bw[t]);
  st_ln(yr + t + 256, (v1 - mu) * rs * gw[t + 256] + bw[t + 256]);
  st_ln(yr + t + 512, (v2 - mu) * rs * gw[t + 512] + bw[t + 512]);
}

// ---------------- assemble x = [cls; tok] + pos ----------------
__global__ __launch_bounds__(256) void assemble_x(const float* __restrict__ tokf,
                                                  const float* __restrict__ cls,
                                                  const float* __restrict__ pos,
                                                  float* __restrict__ x12) {
  const int row = blockIdx.x;  // n*197 + s
  const int n = row / S_, s = row % S_;
  for (int d = threadIdx.x; d < D_; d += 256) {
    float v = (s == 0) ? cls[d] : tokf[(size_t)(n * LTOK_ + s - 1) * D_ + d];
    x12[(size_t)row * D_ + d] = v + pos[s * D_ + d];
  }
}

// ---------------- xa = xa + 2 * (s==0 ? xb : xb*pm) ----------------
__global__ __launch_bounds__(256) void combine_kernel(float* __restrict__ xa,
                                                      const float* __restrict__ xb,
                                                      const float* __restrict__ pm) {
  const int row = blockIdx.x;  // b*197 + s, b<16
  const int b = row / S_, s = row % S_;
  const float m2 = (s == 0) ? 2.f : 2.f * pm[b * LTOK_ + s - 1];
  for (int d = threadIdx.x; d < D_; d += 256) {
    const size_t o = (size_t)row * D_ + d;
    xa[o] += m2 * xb[o];
  }
}

// ---------------- MFMA attention: one block per (b,h) ----------------
// Queries padded to 208 (13 m-tiles), keys padded to 224 (14 n-tiles, 7 PV k-steps).
// Q/K fragments read directly from global (L2-resident). V transposed into LDS.
// P goes through a per-wave LDS buffer to convert C-layout -> A-layout.
#define KPAD_ 224
#define VSTR_ 232   // 16B-aligned rows, conflict-free b128 access pattern

__global__ __launch_bounds__(256, 2) void attn_kernel(const u16* __restrict__ qkv,
                                                      u16* __restrict__ out,
                                                      const float* __restrict__ pm,
                                                      int useBias) {
  __shared__ __align__(16) u16 Vt[64 * VSTR_];        // Vt[col][key]
  __shared__ __align__(16) u16 Pb4[4 * 16 * VSTR_];   // per-wave P[m][key]
  const int bh = blockIdx.x, b = bh / NH_, h = bh % NH_;
  const int t = threadIdx.x, lane = t & 63, w = t >> 6;
  const int r16 = lane & 15, quad = lane >> 4;

  const u16* Qb = qkv + (size_t)b * S_ * 2304 + h * HD_;
  const u16* Kb = Qb + D_;
  const u16* Vb = Qb + 2 * D_;

  // ---- stage V transposed (zero-pad keys >= S_) ----
#pragma unroll
  for (int it = 0; it < 7; it++) {
    const int lin = it * 256 + t;            // 0..1791
    const int col = lin & 63, k0 = (lin >> 6) << 3;
    u16x8 tmp;
#pragma unroll
    for (int j = 0; j < 8; j++) {
      const int key = k0 + j;
      tmp[j] = (key < S_) ? Vb[(size_t)key * 2304 + col] : (u16)0;
    }
    *(u16x8*)&Vt[col * VSTR_ + k0] = tmp;
  }
  __syncthreads();

  u16* Pb = Pb4 + w * (16 * VSTR_);
  const f32x4 z = {0.f, 0.f, 0.f, 0.f};

  for (int it = 0; it < 4; it++) {
    int mt = it * 4 + w;
    const bool real = (mt < 13);
    if (!real) mt = 12;
    const int qbase = mt * 16;

    // ---- scores: S = Q @ K^T (A, B frags straight from global) ----
    const u16* qrow = Qb + (size_t)(qbase + r16) * 2304 + quad * 8;
    const bf16x8 a0 = *(const bf16x8*)(qrow);
    const bf16x8 a1 = *(const bf16x8*)(qrow + 32);
    f32x4 c[14];
#pragma unroll
    for (int nt = 0; nt < 14; nt++) {
      const u16* krow = Kb + (size_t)(nt * 16 + r16) * 2304 + quad * 8;
      const bf16x8 b0 = *(const bf16x8*)(krow);
      const bf16x8 b1 = *(const bf16x8*)(krow + 32);
      f32x4 cc = __builtin_amdgcn_mfma_f32_16x16x32_bf16(a0, b0, z, 0, 0, 0);
      c[nt] = __builtin_amdgcn_mfma_f32_16x16x32_bf16(a1, b1, cc, 0, 0, 0);
    }

    // ---- softmax over keys (rows live in one quad; cols across 16 lanes) ----
    float mx[4] = {-3.0e38f, -3.0e38f, -3.0e38f, -3.0e38f};
#pragma unroll
    for (int nt = 0; nt < 14; nt++) {
      const int key = nt * 16 + r16;
      if (key >= S_) {
#pragma unroll
        for (int r = 0; r < 4; r++) c[nt][r] = -1e30f;  // overwrite kills garbage
      } else {
#pragma unroll
        for (int r = 0; r < 4; r++) c[nt][r] *= 0.125f;
        if (useBias && mt == 0 && quad == 0 && key >= 1)
          c[nt][0] += (pm[b * LTOK_ + key - 1] != 0.f) ? 0.f : -1e30f;
      }
#pragma unroll
      for (int r = 0; r < 4; r++) mx[r] = fmaxf(mx[r], c[nt][r]);
    }
#pragma unroll
    for (int off = 1; off < 16; off <<= 1)
#pragma unroll
      for (int r = 0; r < 4; r++) mx[r] = fmaxf(mx[r], __shfl_xor(mx[r], off));
    float sum[4] = {0.f, 0.f, 0.f, 0.f};
#pragma unroll
    for (int nt = 0; nt < 14; nt++)
#pragma unroll
      for (int r = 0; r < 4; r++) {
        const float e = __expf(c[nt][r] - mx[r]);
        c[nt][r] = e;
        sum[r] += e;
      }
#pragma unroll
    for (int off = 1; off < 16; off <<= 1)
#pragma unroll
      for (int r = 0; r < 4; r++) sum[r] += __shfl_xor(sum[r], off);
    float inv[4];
#pragma unroll
    for (int r = 0; r < 4; r++) inv[r] = 1.f / sum[r];

    // ---- P: C-layout -> LDS -> A-layout ----
#pragma unroll
    for (int nt = 0; nt < 14; nt++)
#pragma unroll
      for (int r = 0; r < 4; r++)
        Pb[(quad * 4 + r) * VSTR_ + nt * 16 + r16] = f2bf(c[nt][r] * inv[r]);
    __syncthreads();

    // ---- O = P @ V ----
    f32x4 ov[4] = {z, z, z, z};
#pragma unroll
    for (int kk = 0; kk < 7; kk++) {
      const bf16x8 pa = *(const bf16x8*)(Pb + r16 * VSTR_ + kk * 32 + quad * 8);
#pragma unroll
      for (int vt = 0; vt < 4; vt++) {
        const bf16x8 vb = *(const bf16x8*)(Vt + (vt * 16 + r16) * VSTR_ + kk * 32 + quad * 8);
        ov[vt] = __builtin_amdgcn_mfma_f32_16x16x32_bf16(pa, vb, ov[vt], 0, 0, 0);
      }
    }
    if (real) {
#pragma unroll
      for (int r = 0; r < 4; r++) {
        const int qq = qbase + quad * 4 + r;
        if (qq < S_) {
#pragma unroll
          for (int vt = 0; vt < 4; vt++)
            out[(size_t)(b * S_ + qq) * D_ + h * HD_ + vt * 16 + r16] = f2bf(ov[vt][r]);
        }
      }
    }
    __syncthreads();  // P buffer reused next iteration
  }
}

// ---------------- final: out = cls_ln @ proj (768x512), fp32 ----------------
__global__ __launch_bounds__(256) void final_proj_kernel(const float* __restrict__ clsn,
                                                         const float* __restrict__ proj,
                                                         float* __restrict__ outp) {
  __shared__ float cs[D_];
  const int b = blockIdx.x;
  for (int d = threadIdx.x; d < D_; d += 256) cs[d] = clsn[b * D_ + d];
  __syncthreads();
  for (int o = threadIdx.x; o < OUT_; o += 256) {
    float acc = 0.f;
    for (int d = 0; d < D_; d++) acc += cs[d] * proj[d * OUT_ + o];
    outp[b * OUT_ + o] = acc;
  }
}

extern "C" void kernel_launch(void* const* d_in, const int* in_sizes, int n_in,
                              void* d_out, int out_size, void* d_ws, size_t ws_size,
                              hipStream_t stream) {
  (void)in_sizes; (void)n_in; (void)out_size; (void)ws_size;
  const float* masked   = (const float*)d_in[0];
  const float* prompted = (const float*)d_in[1];
  const float* pmasks   = (const float*)d_in[2];
  const float* conv_w   = (const float*)d_in[3];
  const float* class_emb= (const float*)d_in[4];
  const float* pos_emb  = (const float*)d_in[5];
  const float* ln_pre_g = (const float*)d_in[6];
  const float* ln_pre_b = (const float*)d_in[7];
  const float* Wqkv     = (const float*)d_in[8];
  const float* bqkv     = (const float*)d_in[9];
  const float* Wo       = (const float*)d_in[10];
  const float* bo       = (const float*)d_in[11];
  const float* ln1_g    = (const float*)d_in[12];
  const float* ln1_b    = (const float*)d_in[13];
  const float* ln2_g    = (const float*)d_in[14];
  const float* ln2_b    = (const float*)d_in[15];
  const float* Wfc      = (const float*)d_in[16];
  const float* bfc      = (const float*)d_in[17];
  const float* Wp       = (const float*)d_in[18];
  const float* bp       = (const float*)d_in[19];
  const float* ln_post_g= (const float*)d_in[20];
  const float* ln_post_b= (const float*)d_in[21];
  const float* projw    = (const float*)d_in[22];

  char* pws = (char*)d_ws;
  auto take = [&](size_t bytes) { char* r = pws; pws += (bytes + 255) & ~(size_t)255; return r; };
  u16*   wqkv_all = (u16*)take((size_t)LAYERS_ * 2304 * D_ * 2);
  u16*   wo_all   = (u16*)take((size_t)LAYERS_ * D_ * D_ * 2);
  u16*   wfc_all  = (u16*)take((size_t)LAYERS_ * FF_ * D_ * 2);
  u16*   wp_all   = (u16*)take((size_t)LAYERS_ * D_ * FF_ * 2);
  u16*   wc       = (u16*)take((size_t)D_ * D_ * 2);
  u16*   Xp       = (u16*)take((size_t)6272 * D_ * 2);
  float* tokf     = (float*)take((size_t)6272 * D_ * 4);
  float* x12      = (float*)take((size_t)6400 * D_ * 4);
  u16*   xn       = (u16*)take((size_t)6400 * D_ * 2);
  u16*   qkvb     = (u16*)take((size_t)6400 * 2304 * 2);
  u16*   ao       = (u16*)take((size_t)6400 * D_ * 2);
  u16*   hb       = (u16*)take((size_t)6400 * FF_ * 2);
  float* xa       = (float*)take((size_t)3200 * D_ * 4);
  float* xb       = (float*)take((size_t)3200 * D_ * 4);
  float* clsn     = (float*)take((size_t)16 * D_ * 4);

  auto cvt = [&](const float* s, u16* d, size_t n) {
    int n4 = (int)(n >> 2);
    cvt_kernel<<<dim3((n4 + 255) / 256), dim3(256), 0, stream>>>(s, d, n4);
  };
  cvt(Wqkv,   wqkv_all, (size_t)LAYERS_ * 2304 * D_);
  cvt(Wo,     wo_all,   (size_t)LAYERS_ * D_ * D_);
  cvt(Wfc,    wfc_all,  (size_t)LAYERS_ * FF_ * D_);
  cvt(Wp,     wp_all,   (size_t)LAYERS_ * D_ * FF_);
  cvt(conv_w, wc,       (size_t)D_ * D_);

  // patch embed for both image sets (32 images)
  im2col_kernel<<<dim3(6272), dim3(256), 0, stream>>>(masked, prompted, Xp);
  gemm_bt<0><<<dim3(6, 49), dim3(256), 0, stream>>>(Xp, wc, nullptr, tokf, nullptr, 6272, D_, D_);
  assemble_x<<<dim3(32 * S_), dim3(256), 0, stream>>>(tokf, class_emb, pos_emb, x12);
  ln_rows<float><<<dim3(32 * S_), dim3(256), 0, stream>>>(x12, D_, x12, D_, ln_pre_g, ln_pre_b);

  auto run_block = [&](float* x, int Mp, int Mv, int Batt, int li, int useBias) {
    const int gy = Mp / 128;
    ln_rows<u16><<<dim3(Mv), dim3(256), 0, stream>>>(x, D_, xn, D_, ln1_g + li * D_, ln1_b + li * D_);
    gemm_bt<1><<<dim3(18, gy), dim3(256), 0, stream>>>(
        xn, wqkv_all + (size_t)li * 2304 * D_, bqkv + li * 2304, nullptr, qkvb, Mp, 2304, D_);
    attn_kernel<<<dim3(Batt * NH_), dim3(256), 0, stream>>>(qkvb, ao, pmasks, useBias);
    gemm_bt<3><<<dim3(6, gy), dim3(256), 0, stream>>>(
        ao, wo_all + (size_t)li * D_ * D_, bo + li * D_, x, nullptr, Mp, D_, D_);
    ln_rows<u16><<<dim3(Mv), dim3(256), 0, stream>>>(x, D_, xn, D_, ln2_g + li * D_, ln2_b + li * D_);
    gemm_bt<2><<<dim3(24, gy), dim3(256), 0, stream>>>(
        xn, wfc_all + (size_t)li * FF_ * D_, bfc + li * FF_, nullptr, hb, Mp, FF_, D_);
    gemm_bt<3><<<dim3(6, gy), dim3(256), 0, stream>>>(
        hb, wp_all + (size_t)li * D_ * FF_, bp + li * D_, x, nullptr, Mp, D_, FF_);
  };

  for (int li = 0; li < 10; li++) run_block(x12, 6400, 32 * S_, 32, li, 0);

  // split into x (masked path) and x2 (prompted path)
  hipMemcpyAsync(xa, x12, (size_t)NIMG_ * S_ * D_ * 4, hipMemcpyDeviceToDevice, stream);
  hipMemcpyAsync(xb, x12 + (size_t)NIMG_ * S_ * D_, (size_t)NIMG_ * S_ * D_ * 4,
                 hipMemcpyDeviceToDevice, stream);

  for (int li = 10; li <= 11; li++) {
    combine_kernel<<<dim3(NIMG_ * S_), dim3(256), 0, stream>>>(xa, xb, pmasks);
    run_block(xa, 3200, NIMG_ * S_, NIMG_, li, 0);
    run_block(xb, 3200, NIMG_ * S_, NIMG_, li, 1);
  }

  ln_rows<float><<<dim3(16), dim3(256), 0, stream>>>(xa, (size_t)S_ * D_, clsn, D_,
                                                     ln_post_g, ln_post_b);
  final_proj_kernel<<<dim3(16), dim3(256), 0, stream>>>(clsn, projw, (float*)d_out);
}

// Round 3
// 3497.749 us; speedup vs baseline: 2.7643x; 1.1084x over previous
//
#include <hip/hip_runtime.h>
#include <cstdint>
#include <cstddef>

#define D_ 768
#define NH_ 12
#define HD_ 64
#define S_ 197
#define LTOK_ 196
#define FF_ 3072
#define NIMG_ 16
#define OUT_ 512
#define LAYERS_ 12

typedef unsigned short u16;
typedef __bf16 bf16x8 __attribute__((ext_vector_type(8)));
typedef float f32x4 __attribute__((ext_vector_type(4)));
typedef u16 u16x8 __attribute__((ext_vector_type(8)));

__device__ __forceinline__ u16 f2bf(float f) {
  uint32_t u = __builtin_bit_cast(uint32_t, f);
  u = (u + 0x7FFFu + ((u >> 16) & 1u)) >> 16;
  return (u16)u;
}

typedef __attribute__((address_space(3))) void lvoid;
typedef __attribute__((address_space(1))) void gvoid;
__device__ __forceinline__ void async16(const u16* g, u16* l) {
  __builtin_amdgcn_global_load_lds((gvoid*)(uintptr_t)g,
                                   (lvoid*)(uint32_t)(uintptr_t)l, 16, 0, 0);
}

// ---------------- fp32 -> bf16 convert ----------------
__global__ __launch_bounds__(256) void cvt_kernel(const float* __restrict__ src,
                                                  u16* __restrict__ dst, int n4) {
  int i = blockIdx.x * 256 + threadIdx.x;
  if (i >= n4) return;
  const float4 v = ((const float4*)src)[i];
  ushort4 o;
  o.x = f2bf(v.x); o.y = f2bf(v.y); o.z = f2bf(v.z); o.w = f2bf(v.w);
  ((ushort4*)dst)[i] = o;
}

// ---------------- im2col for patch conv ----------------
__global__ __launch_bounds__(256) void im2col_kernel(const float* __restrict__ mimg,
                                                     const float* __restrict__ pimg,
                                                     u16* __restrict__ Xp) {
  const int row = blockIdx.x;                 // 0..6271  (n*196 + l)
  const int n = row / LTOK_, l = row % LTOK_;
  const float* img = (n < NIMG_) ? (mimg + (size_t)n * 3 * 224 * 224)
                                 : (pimg + (size_t)(n - NIMG_) * 3 * 224 * 224);
  const int gy = l / 14, gx = l % 14;
  for (int col = threadIdx.x; col < D_; col += 256) {
    const int c = col >> 8, py = (col >> 4) & 15, px = col & 15;
    Xp[(size_t)row * D_ + col] = f2bf(img[c * 50176 + (gy * 16 + py) * 224 + gx * 16 + px]);
  }
}

// ---------------- GEMM: C = A(M,K) @ Bw(N,K)^T (+epilogue) ----------------
// 1D grid, panel-swizzled: panels of 8 gy rows x all gx, gy fastest inside a
// panel (consecutive blocks -> different XCDs -> share one B-tile; B stays
// L2-resident per XCD, A strips read ~once).
// BK=64 as two 32-wide sub-buffers (keeps global_load_lds contiguity + the
// proven LDS bank profile), halving barrier drains vs BK=32.
template <int EPI>
__global__ __launch_bounds__(256, 2) void gemm_bt(const u16* __restrict__ A,
                                                  const u16* __restrict__ Bw,
                                                  const float* __restrict__ bias,
                                                  float* __restrict__ Cf,
                                                  u16* __restrict__ Cb,
                                                  int M, int N, int K,
                                                  int gxN, int gyN) {
  __shared__ __align__(16) u16 As[2][128 * 32];
  __shared__ __align__(16) u16 Bs[2][128 * 32];
  const int t = threadIdx.x, lane = t & 63, w = t >> 6;
  const int wm = (w >> 1) << 6, wn = (w & 1) << 6;

  // panel swizzle
  const int id = blockIdx.x;
  const int panelBlocks = gxN << 3;
  const int p = id / panelBlocks;
  const int lid = id - p * panelBlocks;
  const int prm = gyN - (p << 3);
  const int pr = prm < 8 ? prm : 8;
  const int gy = (p << 3) + lid % pr;
  const int gx = lid / pr;
  const int mBase = gy << 7, nBase = gx << 7;

  f32x4 acc[4][4];
  const f32x4 z = {0.f, 0.f, 0.f, 0.f};
#pragma unroll
  for (int i = 0; i < 4; i++)
#pragma unroll
    for (int j = 0; j < 4; j++) acc[i][j] = z;

  const int lr = t >> 2, lc = (t & 3) << 3;
  const u16* Ag = A + (size_t)(mBase + lr) * K + lc;
  const u16* Bg = Bw + (size_t)(nBase + lr) * K + lc;
  const size_t halfs = (size_t)64 * K;
  u16* Al0 = As[0] + t * 8;  u16* Al1 = As[1] + t * 8;
  u16* Bl0 = Bs[0] + t * 8;  u16* Bl1 = Bs[1] + t * 8;
  const int q8 = (lane >> 4) << 3, r16 = lane & 15;

  for (int k0 = 0; k0 < K; k0 += 64) {
    async16(Ag,          Al0);  async16(Ag + halfs,      Al0 + 2048);
    async16(Ag + 32,     Al1);  async16(Ag + 32 + halfs, Al1 + 2048);
    async16(Bg,          Bl0);  async16(Bg + halfs,      Bl0 + 2048);
    async16(Bg + 32,     Bl1);  async16(Bg + 32 + halfs, Bl1 + 2048);
    Ag += 64; Bg += 64;
    __syncthreads();
#pragma unroll
    for (int kh = 0; kh < 2; kh++) {
      bf16x8 af[4], bfr[4];
#pragma unroll
      for (int mt = 0; mt < 4; mt++)
        af[mt] = *(const bf16x8*)(As[kh] + (wm + mt * 16 + r16) * 32 + q8);
#pragma unroll
      for (int nt = 0; nt < 4; nt++)
        bfr[nt] = *(const bf16x8*)(Bs[kh] + (wn + nt * 16 + r16) * 32 + q8);
#pragma unroll
      for (int mt = 0; mt < 4; mt++)
#pragma unroll
        for (int nt = 0; nt < 4; nt++)
          acc[mt][nt] = __builtin_amdgcn_mfma_f32_16x16x32_bf16(af[mt], bfr[nt], acc[mt][nt], 0, 0, 0);
    }
    __syncthreads();
  }

  const int colB = nBase + wn + r16;
  const int rowB = mBase + wm + ((lane >> 4) << 2);
#pragma unroll
  for (int nt = 0; nt < 4; nt++) {
    const int col = colB + nt * 16;
    const float bv = (EPI == 0) ? 0.f : bias[col];
#pragma unroll
    for (int mt = 0; mt < 4; mt++) {
#pragma unroll
      for (int r = 0; r < 4; r++) {
        const int row = rowB + mt * 16 + r;
        const size_t o = (size_t)row * N + col;
        const float v = acc[mt][nt][r];
        if (EPI == 0) {
          Cf[o] = v;
        } else if (EPI == 1) {
          Cb[o] = f2bf(v + bv);
        } else if (EPI == 2) {
          const float hh = v + bv;
          Cb[o] = f2bf(hh / (1.f + __expf(-1.702f * hh)));
        } else {
          Cf[o] += v + bv;
        }
      }
    }
  }
}

// ---------------- LayerNorm over rows of 768 ----------------
__device__ __forceinline__ void st_ln(float* p, float v) { *p = v; }
__device__ __forceinline__ void st_ln(u16* p, float v) { *p = f2bf(v); }

template <typename OT>
__global__ __launch_bounds__(256) void ln_rows(const float* __restrict__ x, size_t strideIn,
                                               OT* __restrict__ y, size_t strideOut,
                                               const float* __restrict__ gw,
                                               const float* __restrict__ bw) {
  const int row = blockIdx.x, t = threadIdx.x;
  const float* xr = x + (size_t)row * strideIn;
  float v0 = xr[t], v1 = xr[t + 256], v2 = xr[t + 512];
  float s1 = v0 + v1 + v2;
  float s2 = v0 * v0 + v1 * v1 + v2 * v2;
#pragma unroll
  for (int off = 1; off < 64; off <<= 1) {
    s1 += __shfl_xor(s1, off);
    s2 += __shfl_xor(s2, off);
  }
  __shared__ float as1[4], as2[4];
  const int lane = t & 63, w = t >> 6;
  if (lane == 0) { as1[w] = s1; as2[w] = s2; }
  __syncthreads();
  s1 = as1[0] + as1[1] + as1[2] + as1[3];
  s2 = as2[0] + as2[1] + as2[2] + as2[3];
  const float mu = s1 * (1.f / 768.f);
  const float rs = rsqrtf(fmaxf(s2 * (1.f / 768.f) - mu * mu, 0.f) + 1e-5f);
  OT* yr = y + (size_t)row * strideOut;
  st_ln(yr + t, (v0 - mu) * rs * gw[t] + bw[t]);
  st_ln(yr + t + 256, (v1 - mu) * rs * gw[t + 256] + bw[t + 256]);
  st_ln(yr + t + 512, (v2 - mu) * rs * gw[t + 512] + bw[t + 512]);
}

// ---------------- assemble x = [cls; tok] + pos ----------------
__global__ __launch_bounds__(256) void assemble_x(const float* __restrict__ tokf,
                                                  const float* __restrict__ cls,
                                                  const float* __restrict__ pos,
                                                  float* __restrict__ x12) {
  const int row = blockIdx.x;  // n*197 + s
  const int n = row / S_, s = row % S_;
  for (int d = threadIdx.x; d < D_; d += 256) {
    float v = (s == 0) ? cls[d] : tokf[(size_t)(n * LTOK_ + s - 1) * D_ + d];
    x12[(size_t)row * D_ + d] = v + pos[s * D_ + d];
  }
}

// ---------------- xa = xa + 2 * (s==0 ? xb : xb*pm) ----------------
__global__ __launch_bounds__(256) void combine_kernel(float* __restrict__ xa,
                                                      const float* __restrict__ xb,
                                                      const float* __restrict__ pm) {
  const int row = blockIdx.x;  // b*197 + s, b<16
  const int b = row / S_, s = row % S_;
  const float m2 = (s == 0) ? 2.f : 2.f * pm[b * LTOK_ + s - 1];
  for (int d = threadIdx.x; d < D_; d += 256) {
    const size_t o = (size_t)row * D_ + d;
    xa[o] += m2 * xb[o];
  }
}

// ---------------- MFMA attention: one block per (b,h) ----------------
#define VSTR_ 232   // 16B-aligned rows, conflict-free b128 access pattern

__global__ __launch_bounds__(256, 2) void attn_kernel(const u16* __restrict__ qkv,
                                                      u16* __restrict__ out,
                                                      const float* __restrict__ pm,
                                                      int useBias) {
  __shared__ __align__(16) u16 Vt[64 * VSTR_];        // Vt[col][key]
  __shared__ __align__(16) u16 Pb4[4 * 16 * VSTR_];   // per-wave P[m][key]
  const int bh = blockIdx.x, b = bh / NH_, h = bh % NH_;
  const int t = threadIdx.x, lane = t & 63, w = t >> 6;
  const int r16 = lane & 15, quad = lane >> 4;

  const u16* Qb = qkv + (size_t)b * S_ * 2304 + h * HD_;
  const u16* Kb = Qb + D_;
  const u16* Vb = Qb + 2 * D_;

  // ---- stage V transposed (zero-pad keys >= S_) ----
#pragma unroll
  for (int it = 0; it < 7; it++) {
    const int lin = it * 256 + t;            // 0..1791
    const int col = lin & 63, k0 = (lin >> 6) << 3;
    u16x8 tmp;
#pragma unroll
    for (int j = 0; j < 8; j++) {
      const int key = k0 + j;
      tmp[j] = (key < S_) ? Vb[(size_t)key * 2304 + col] : (u16)0;
    }
    *(u16x8*)&Vt[col * VSTR_ + k0] = tmp;
  }
  __syncthreads();

  u16* Pb = Pb4 + w * (16 * VSTR_);
  const f32x4 z = {0.f, 0.f, 0.f, 0.f};

  for (int it = 0; it < 4; it++) {
    int mt = it * 4 + w;
    const bool real = (mt < 13);
    if (!real) mt = 12;
    const int qbase = mt * 16;

    // ---- scores: S = Q @ K^T (A, B frags straight from global) ----
    const u16* qrow = Qb + (size_t)(qbase + r16) * 2304 + quad * 8;
    const bf16x8 a0 = *(const bf16x8*)(qrow);
    const bf16x8 a1 = *(const bf16x8*)(qrow + 32);
    f32x4 c[14];
#pragma unroll
    for (int nt = 0; nt < 14; nt++) {
      const u16* krow = Kb + (size_t)(nt * 16 + r16) * 2304 + quad * 8;
      const bf16x8 b0 = *(const bf16x8*)(krow);
      const bf16x8 b1 = *(const bf16x8*)(krow + 32);
      f32x4 cc = __builtin_amdgcn_mfma_f32_16x16x32_bf16(a0, b0, z, 0, 0, 0);
      c[nt] = __builtin_amdgcn_mfma_f32_16x16x32_bf16(a1, b1, cc, 0, 0, 0);
    }

    // ---- softmax over keys ----
    float mx[4] = {-3.0e38f, -3.0e38f, -3.0e38f, -3.0e38f};
#pragma unroll
    for (int nt = 0; nt < 14; nt++) {
      const int key = nt * 16 + r16;
      if (key >= S_) {
#pragma unroll
        for (int r = 0; r < 4; r++) c[nt][r] = -1e30f;
      } else {
#pragma unroll
        for (int r = 0; r < 4; r++) c[nt][r] *= 0.125f;
        if (useBias && mt == 0 && quad == 0 && key >= 1)
          c[nt][0] += (pm[b * LTOK_ + key - 1] != 0.f) ? 0.f : -1e30f;
      }
#pragma unroll
      for (int r = 0; r < 4; r++) mx[r] = fmaxf(mx[r], c[nt][r]);
    }
#pragma unroll
    for (int off = 1; off < 16; off <<= 1)
#pragma unroll
      for (int r = 0; r < 4; r++) mx[r] = fmaxf(mx[r], __shfl_xor(mx[r], off));
    float sum[4] = {0.f, 0.f, 0.f, 0.f};
#pragma unroll
    for (int nt = 0; nt < 14; nt++)
#pragma unroll
      for (int r = 0; r < 4; r++) {
        const float e = __expf(c[nt][r] - mx[r]);
        c[nt][r] = e;
        sum[r] += e;
      }
#pragma unroll
    for (int off = 1; off < 16; off <<= 1)
#pragma unroll
      for (int r = 0; r < 4; r++) sum[r] += __shfl_xor(sum[r], off);
    float inv[4];
#pragma unroll
    for (int r = 0; r < 4; r++) inv[r] = 1.f / sum[r];

    // ---- P: C-layout -> LDS -> A-layout ----
#pragma unroll
    for (int nt = 0; nt < 14; nt++)
#pragma unroll
      for (int r = 0; r < 4; r++)
        Pb[(quad * 4 + r) * VSTR_ + nt * 16 + r16] = f2bf(c[nt][r] * inv[r]);
    __syncthreads();

    // ---- O = P @ V ----
    f32x4 ov[4] = {z, z, z, z};
#pragma unroll
    for (int kk = 0; kk < 7; kk++) {
      const bf16x8 pa = *(const bf16x8*)(Pb + r16 * VSTR_ + kk * 32 + quad * 8);
#pragma unroll
      for (int vt = 0; vt < 4; vt++) {
        const bf16x8 vb = *(const bf16x8*)(Vt + (vt * 16 + r16) * VSTR_ + kk * 32 + quad * 8);
        ov[vt] = __builtin_amdgcn_mfma_f32_16x16x32_bf16(pa, vb, ov[vt], 0, 0, 0);
      }
    }
    if (real) {
#pragma unroll
      for (int r = 0; r < 4; r++) {
        const int qq = qbase + quad * 4 + r;
        if (qq < S_) {
#pragma unroll
          for (int vt = 0; vt < 4; vt++)
            out[(size_t)(b * S_ + qq) * D_ + h * HD_ + vt * 16 + r16] = f2bf(ov[vt][r]);
        }
      }
    }
    __syncthreads();  // P buffer reused next iteration
  }
}

// ---------------- final: out = cls_ln @ proj (768x512), fp32 ----------------
__global__ __launch_bounds__(256) void final_proj_kernel(const float* __restrict__ clsn,
                                                         const float* __restrict__ proj,
                                                         float* __restrict__ outp) {
  __shared__ float cs[D_];
  const int b = blockIdx.x;
  for (int d = threadIdx.x; d < D_; d += 256) cs[d] = clsn[b * D_ + d];
  __syncthreads();
  for (int o = threadIdx.x; o < OUT_; o += 256) {
    float acc = 0.f;
    for (int d = 0; d < D_; d++) acc += cs[d] * proj[d * OUT_ + o];
    outp[b * OUT_ + o] = acc;
  }
}

extern "C" void kernel_launch(void* const* d_in, const int* in_sizes, int n_in,
                              void* d_out, int out_size, void* d_ws, size_t ws_size,
                              hipStream_t stream) {
  (void)in_sizes; (void)n_in; (void)out_size; (void)ws_size;
  const float* masked   = (const float*)d_in[0];
  const float* prompted = (const float*)d_in[1];
  const float* pmasks   = (const float*)d_in[2];
  const float* conv_w   = (const float*)d_in[3];
  const float* class_emb= (const float*)d_in[4];
  const float* pos_emb  = (const float*)d_in[5];
  const float* ln_pre_g = (const float*)d_in[6];
  const float* ln_pre_b = (const float*)d_in[7];
  const float* Wqkv     = (const float*)d_in[8];
  const float* bqkv     = (const float*)d_in[9];
  const float* Wo       = (const float*)d_in[10];
  const float* bo       = (const float*)d_in[11];
  const float* ln1_g    = (const float*)d_in[12];
  const float* ln1_b    = (const float*)d_in[13];
  const float* ln2_g    = (const float*)d_in[14];
  const float* ln2_b    = (const float*)d_in[15];
  const float* Wfc      = (const float*)d_in[16];
  const float* bfc      = (const float*)d_in[17];
  const float* Wp       = (const float*)d_in[18];
  const float* bp       = (const float*)d_in[19];
  const float* ln_post_g= (const float*)d_in[20];
  const float* ln_post_b= (const float*)d_in[21];
  const float* projw    = (const float*)d_in[22];

  char* pws = (char*)d_ws;
  auto take = [&](size_t bytes) { char* r = pws; pws += (bytes + 255) & ~(size_t)255; return r; };
  u16*   wqkv_all = (u16*)take((size_t)LAYERS_ * 2304 * D_ * 2);
  u16*   wo_all   = (u16*)take((size_t)LAYERS_ * D_ * D_ * 2);
  u16*   wfc_all  = (u16*)take((size_t)LAYERS_ * FF_ * D_ * 2);
  u16*   wp_all   = (u16*)take((size_t)LAYERS_ * D_ * FF_ * 2);
  u16*   wc       = (u16*)take((size_t)D_ * D_ * 2);
  u16*   Xp       = (u16*)take((size_t)6272 * D_ * 2);
  float* tokf     = (float*)take((size_t)6272 * D_ * 4);
  float* x12      = (float*)take((size_t)6400 * D_ * 4);
  u16*   xn       = (u16*)take((size_t)6400 * D_ * 2);
  u16*   qkvb     = (u16*)take((size_t)6400 * 2304 * 2);
  u16*   ao       = (u16*)take((size_t)6400 * D_ * 2);
  u16*   hb       = (u16*)take((size_t)6400 * FF_ * 2);
  float* xa       = (float*)take((size_t)3200 * D_ * 4);
  float* xb       = (float*)take((size_t)3200 * D_ * 4);
  float* clsn     = (float*)take((size_t)16 * D_ * 4);

  auto cvt = [&](const float* s, u16* d, size_t n) {
    int n4 = (int)(n >> 2);
    cvt_kernel<<<dim3((n4 + 255) / 256), dim3(256), 0, stream>>>(s, d, n4);
  };
  cvt(Wqkv,   wqkv_all, (size_t)LAYERS_ * 2304 * D_);
  cvt(Wo,     wo_all,   (size_t)LAYERS_ * D_ * D_);
  cvt(Wfc,    wfc_all,  (size_t)LAYERS_ * FF_ * D_);
  cvt(Wp,     wp_all,   (size_t)LAYERS_ * D_ * FF_);
  cvt(conv_w, wc,       (size_t)D_ * D_);

  // patch embed for both image sets (32 images)
  im2col_kernel<<<dim3(6272), dim3(256), 0, stream>>>(masked, prompted, Xp);
  gemm_bt<0><<<dim3(6 * 49), dim3(256), 0, stream>>>(Xp, wc, nullptr, tokf, nullptr,
                                                     6272, D_, D_, 6, 49);
  assemble_x<<<dim3(32 * S_), dim3(256), 0, stream>>>(tokf, class_emb, pos_emb, x12);
  ln_rows<float><<<dim3(32 * S_), dim3(256), 0, stream>>>(x12, D_, x12, D_, ln_pre_g, ln_pre_b);

  auto run_block = [&](float* x, int Mp, int Mv, int Batt, int li, int useBias) {
    const int gy = Mp / 128;
    ln_rows<u16><<<dim3(Mv), dim3(256), 0, stream>>>(x, D_, xn, D_, ln1_g + li * D_, ln1_b + li * D_);
    gemm_bt<1><<<dim3(18 * gy), dim3(256), 0, stream>>>(
        xn, wqkv_all + (size_t)li * 2304 * D_, bqkv + li * 2304, nullptr, qkvb,
        Mp, 2304, D_, 18, gy);
    attn_kernel<<<dim3(Batt * NH_), dim3(256), 0, stream>>>(qkvb, ao, pmasks, useBias);
    gemm_bt<3><<<dim3(6 * gy), dim3(256), 0, stream>>>(
        ao, wo_all + (size_t)li * D_ * D_, bo + li * D_, x, nullptr,
        Mp, D_, D_, 6, gy);
    ln_rows<u16><<<dim3(Mv), dim3(256), 0, stream>>>(x, D_, xn, D_, ln2_g + li * D_, ln2_b + li * D_);
    gemm_bt<2><<<dim3(24 * gy), dim3(256), 0, stream>>>(
        xn, wfc_all + (size_t)li * FF_ * D_, bfc + li * FF_, nullptr, hb,
        Mp, FF_, D_, 24, gy);
    gemm_bt<3><<<dim3(6 * gy), dim3(256), 0, stream>>>(
        hb, wp_all + (size_t)li * D_ * FF_, bp + li * D_, x, nullptr,
        Mp, D_, FF_, 6, gy);
  };

  for (int li = 0; li < 10; li++) run_block(x12, 6400, 32 * S_, 32, li, 0);

  // split into x (masked path) and x2 (prompted path)
  hipMemcpyAsync(xa, x12, (size_t)NIMG_ * S_ * D_ * 4, hipMemcpyDeviceToDevice, stream);
  hipMemcpyAsync(xb, x12 + (size_t)NIMG_ * S_ * D_, (size_t)NIMG_ * S_ * D_ * 4,
                 hipMemcpyDeviceToDevice, stream);

  for (int li = 10; li <= 11; li++) {
    combine_kernel<<<dim3(NIMG_ * S_), dim3(256), 0, stream>>>(xa, xb, pmasks);
    run_block(xa, 3200, NIMG_ * S_, NIMG_, li, 0);
    run_block(xb, 3200, NIMG_ * S_, NIMG_, li, 1);
  }

  ln_rows<float><<<dim3(16), dim3(256), 0, stream>>>(xa, (size_t)S_ * D_, clsn, D_,
                                                     ln_post_g, ln_post_b);
  final_proj_kernel<<<dim3(16), dim3(256), 0, stream>>>(clsn, projw, (float*)d_out);
}